// Round 3
// baseline (261.021 us; speedup 1.0000x reference)
//
#include <hip/hip_runtime.h>

// Problem constants (match reference)
constexpr int B = 128;
constexpr int N = 16384;
constexpr int H = 512;
constexpr int W = 512;
constexpr int HW = H * W;                        // 262144
constexpr long long TOT = (long long)B * HW;     // 33554432 pixels

constexpr int TROWS = 32;                        // rows per tile (64 KiB LDS)
constexpr int NTILES = H / TROWS;                // 16 tiles per frame
constexpr int NBUCKETS = B * NTILES;             // 2048
constexpr int CAP = 2048;                        // slots per bucket (mean ~1056)
constexpr int NGROUPS = B * N / 4;               // 524288 groups of 4 points
constexpr int F4_PER_FRAME = N * 3 / 4;          // 12288 float4 per frame

// ---------------------------------------------------------------------------
// Kernel 1: bin points by (frame, row-tile). Straddlers go into both tiles.
// ---------------------------------------------------------------------------
__global__ void __launch_bounds__(512) k_bin(const float4* __restrict__ pts,
                                             float4* __restrict__ buckets,
                                             unsigned int* __restrict__ cnt) {
    int tid = blockIdx.x * 512 + threadIdx.x;    // one group of 4 points
    if (tid >= NGROUPS) return;
    float4 a = pts[tid * 3 + 0];   // x0 y0 i0 x1
    float4 b = pts[tid * 3 + 1];   // y1 i1 x2 y2
    float4 c = pts[tid * 3 + 2];   // i2 x3 y3 i3
    int frame = tid >> 12;         // 4096 groups per frame
    int fb = frame * NTILES;

    float xs[4] = {a.x, a.w, b.z, c.y};
    float ys[4] = {a.y, b.x, b.w, c.z};
    float is[4] = {a.z, b.y, c.x, c.w};
#pragma unroll
    for (int k = 0; k < 4; ++k) {
        float x = fminf(fmaxf(xs[k], 0.0f), (float)(W - 1));
        float y = fminf(fmaxf(ys[k], 0.0f), (float)(H - 1));
        int y0 = (int)floorf(y);
        int y1 = min(y0 + 1, H - 1);
        int t0 = y0 >> 5;                         // TROWS = 32
        int t1 = y1 >> 5;
        float4 rec = make_float4(x, y, is[k], 0.0f);
        unsigned s0 = atomicAdd(&cnt[fb + t0], 1u);
        if (s0 < (unsigned)CAP)
            buckets[(size_t)(fb + t0) * CAP + s0] = rec;
        if (t1 != t0) {
            unsigned s1 = atomicAdd(&cnt[fb + t1], 1u);
            if (s1 < (unsigned)CAP)
                buckets[(size_t)(fb + t1) * CAP + s1] = rec;
        }
    }
}

// ---------------------------------------------------------------------------
// Kernel 2: per-(frame,tile) LDS splat of its bucket + squared-diff reduce.
// ---------------------------------------------------------------------------
__global__ void __launch_bounds__(512) k_tile(const float4* __restrict__ buckets,
                                              const unsigned int* __restrict__ cnt,
                                              const float* __restrict__ tgt,
                                              double* __restrict__ partials) {
    __shared__ float tile[TROWS * W];            // 64 KiB
    int bid = blockIdx.x;
    int frame = bid >> 4;
    int t = bid & (NTILES - 1);
    int r0 = t * TROWS;

    float4* t4 = (float4*)tile;
    for (int i = threadIdx.x; i < TROWS * W / 4; i += 512)
        t4[i] = make_float4(0.f, 0.f, 0.f, 0.f);
    __syncthreads();

    int n = (int)min(cnt[bid], (unsigned)CAP);
    const float4* bp = buckets + (size_t)bid * CAP;
    for (int i = threadIdx.x; i < n; i += 512) {
        float4 p = bp[i];
        float x = p.x, y = p.y, inten = p.z;
        float x0f = floorf(x), y0f = floorf(y);
        float fx = x - x0f, fy = y - y0f;
        int x0 = (int)x0f, y0 = (int)y0f;
        int x1 = min(x0 + 1, W - 1);
        int y1 = min(y0 + 1, H - 1);
        int ra = y0 - r0;
        int rb = y1 - r0;
        float w00 = inten * (1.0f - fx) * (1.0f - fy);
        float w01 = inten * fx * (1.0f - fy);
        float w10 = inten * (1.0f - fx) * fy;
        float w11 = inten * fx * fy;
        if ((unsigned)ra < (unsigned)TROWS) {
            atomicAdd(&tile[ra * W + x0], w00);
            atomicAdd(&tile[ra * W + x1], w01);
        }
        if ((unsigned)rb < (unsigned)TROWS) {
            atomicAdd(&tile[rb * W + x0], w10);
            atomicAdd(&tile[rb * W + x1], w11);
        }
    }
    __syncthreads();

    const float4* tg = (const float4*)(tgt + (size_t)frame * HW + (size_t)r0 * W);
    double acc = 0.0;
    for (int i = threadIdx.x; i < TROWS * W / 4; i += 512) {
        float4 tv = tg[i];
        float4 sv = t4[i];
        float d0 = sv.x - tv.x;
        float d1 = sv.y - tv.y;
        float d2 = sv.z - tv.z;
        float d3 = sv.w - tv.w;
        acc += (double)(d0 * d0 + d1 * d1) + (double)(d2 * d2 + d3 * d3);
    }

    for (int off = 32; off > 0; off >>= 1)
        acc += __shfl_down(acc, off, 64);
    __syncthreads();                             // tile reads done
    double* sacc = (double*)tile;
    int lane = threadIdx.x & 63;
    int wave = threadIdx.x >> 6;
    if (lane == 0) sacc[wave] = acc;
    __syncthreads();
    if (threadIdx.x == 0) {
        double s = 0.0;
        for (int wv = 0; wv < 8; ++wv) s += sacc[wv];
        partials[bid] = s;
    }
}

// ---------------------------------------------------------------------------
// Kernel 3: final reduce of NBUCKETS partials -> mean -> d_out[0]
// ---------------------------------------------------------------------------
__global__ void __launch_bounds__(256) k_final(const double* __restrict__ partials,
                                               float* __restrict__ out) {
    double acc = 0.0;
    for (int i = threadIdx.x; i < NBUCKETS; i += 256)
        acc += partials[i];
    for (int off = 32; off > 0; off >>= 1)
        acc += __shfl_down(acc, off, 64);
    __shared__ double sacc[4];
    int lane = threadIdx.x & 63;
    int wave = threadIdx.x >> 6;
    if (lane == 0) sacc[wave] = acc;
    __syncthreads();
    if (threadIdx.x == 0) {
        double s = sacc[0] + sacc[1] + sacc[2] + sacc[3];
        out[0] = (float)(s / (double)TOT);
    }
}

// ---------------------------------------------------------------------------
extern "C" void kernel_launch(void* const* d_in, const int* in_sizes, int n_in,
                              void* d_out, int out_size, void* d_ws, size_t ws_size,
                              hipStream_t stream) {
    const float* pts = (const float*)d_in[0];     // [B, N, 3]
    const float* tgt = (const float*)d_in[1];     // [B, H, W]
    float* out = (float*)d_out;

    // ws layout: [ counters 8KB | partials 16KB | pad | buckets 64MiB ]
    unsigned int* cnt = (unsigned int*)d_ws;
    double* partials = (double*)((char*)d_ws + 8192);
    float4* buckets = (float4*)((char*)d_ws + 32768);

    hipMemsetAsync(cnt, 0, NBUCKETS * sizeof(unsigned int), stream);
    k_bin<<<NGROUPS / 512, 512, 0, stream>>>((const float4*)pts, buckets, cnt);
    k_tile<<<NBUCKETS, 512, 0, stream>>>(buckets, cnt, tgt, partials);
    k_final<<<1, 256, 0, stream>>>(partials, out);
}

// Round 4
// 90.113 us; speedup vs baseline: 2.8966x; 2.8966x over previous
//
#include <hip/hip_runtime.h>

// Problem constants (match reference)
constexpr int B = 128;
constexpr int N = 16384;
constexpr int H = 512;
constexpr int W = 512;
constexpr int HW = H * W;                        // 262144
constexpr long long TOT = (long long)B * HW;     // 33554432 pixels

constexpr int TROWS = 16;                        // rows per tile (32 KiB LDS)
constexpr int NTILES = H / TROWS;                // 32 tiles per frame
constexpr int NBUCKETS = B * NTILES;             // 4096
constexpr int CAP = 1024;                        // slots per bucket (mean ~545)
constexpr int NGROUPS = B * N / 4;               // 524288 groups of 4 points
constexpr int BIN_BLOCKS = NGROUPS / 512;        // 1024 (2048 pts/block, 8 blk/frame)

// ---------------------------------------------------------------------------
// Kernel 1: bin points by (frame, row-tile), per-block LDS slot aggregation.
// Each block handles 2048 points of ONE frame (8 blocks per frame).
// ---------------------------------------------------------------------------
__global__ void __launch_bounds__(512) k_bin(const float4* __restrict__ pts,
                                             float4* __restrict__ buckets,
                                             unsigned int* __restrict__ cnt) {
    __shared__ unsigned int lcnt[NTILES];
    __shared__ unsigned int lbase[NTILES];

    int tid = blockIdx.x * 512 + threadIdx.x;    // one group of 4 points
    int frame = tid >> 12;                       // 4096 groups per frame
    int fb = frame * NTILES;

    if (threadIdx.x < NTILES) lcnt[threadIdx.x] = 0;
    __syncthreads();

    float4 a = pts[tid * 3 + 0];   // x0 y0 i0 x1
    float4 b = pts[tid * 3 + 1];   // y1 i1 x2 y2
    float4 c = pts[tid * 3 + 2];   // i2 x3 y3 i3

    float xs[4] = {a.x, a.w, b.z, c.y};
    float ys[4] = {a.y, b.x, b.w, c.z};
    float is[4] = {a.z, b.y, c.x, c.w};

    int tb0[4], sl0[4], tb1[4], sl1[4];
#pragma unroll
    for (int k = 0; k < 4; ++k) {
        float x = fminf(fmaxf(xs[k], 0.0f), (float)(W - 1));
        float y = fminf(fmaxf(ys[k], 0.0f), (float)(H - 1));
        xs[k] = x; ys[k] = y;
        int y0 = (int)floorf(y);
        int y1 = min(y0 + 1, H - 1);
        int t0 = y0 >> 4;                         // TROWS = 16
        int t1 = y1 >> 4;
        tb0[k] = t0;
        sl0[k] = (int)atomicAdd(&lcnt[t0], 1u);
        if (t1 != t0) {
            tb1[k] = t1;
            sl1[k] = (int)atomicAdd(&lcnt[t1], 1u);
        } else {
            tb1[k] = -1; sl1[k] = 0;
        }
    }
    __syncthreads();

    if (threadIdx.x < NTILES)
        lbase[threadIdx.x] = atomicAdd(&cnt[fb + threadIdx.x], lcnt[threadIdx.x]);
    __syncthreads();

#pragma unroll
    for (int k = 0; k < 4; ++k) {
        float4 rec = make_float4(xs[k], ys[k], is[k], 0.0f);
        unsigned s0 = lbase[tb0[k]] + (unsigned)sl0[k];
        if (s0 < (unsigned)CAP)
            buckets[(size_t)(fb + tb0[k]) * CAP + s0] = rec;
        if (tb1[k] >= 0) {
            unsigned s1 = lbase[tb1[k]] + (unsigned)sl1[k];
            if (s1 < (unsigned)CAP)
                buckets[(size_t)(fb + tb1[k]) * CAP + s1] = rec;
        }
    }
}

// ---------------------------------------------------------------------------
// Kernel 2: per-(frame,tile) block. LDS tile = -target, splat bucket points
// via LDS atomics, then sum of squares (tile already holds splat - target).
// ---------------------------------------------------------------------------
__global__ void __launch_bounds__(512) k_tile(const float4* __restrict__ buckets,
                                              const unsigned int* __restrict__ cnt,
                                              const float* __restrict__ tgt,
                                              double* __restrict__ partials) {
    __shared__ float tile[TROWS * W];            // 32 KiB
    int bid = blockIdx.x;
    int frame = bid >> 5;                        // NTILES = 32
    int t = bid & (NTILES - 1);
    int r0 = t * TROWS;

    // init tile = -target (so after splat, tile holds splat - target)
    float4* t4 = (float4*)tile;
    const float4* tg = (const float4*)(tgt + (size_t)frame * HW + (size_t)r0 * W);
    for (int i = threadIdx.x; i < TROWS * W / 4; i += 512) {
        float4 v = tg[i];
        t4[i] = make_float4(-v.x, -v.y, -v.z, -v.w);
    }
    __syncthreads();

    int n = (int)min(cnt[bid], (unsigned)CAP);
    const float4* bp = buckets + (size_t)bid * CAP;
    for (int i = threadIdx.x; i < n; i += 512) {
        float4 p = bp[i];
        float x = p.x, y = p.y, inten = p.z;
        float x0f = floorf(x), y0f = floorf(y);
        float fx = x - x0f, fy = y - y0f;
        int x0 = (int)x0f, y0 = (int)y0f;
        int x1 = min(x0 + 1, W - 1);
        int y1 = min(y0 + 1, H - 1);
        int ra = y0 - r0;
        int rb = y1 - r0;
        float w00 = inten * (1.0f - fx) * (1.0f - fy);
        float w01 = inten * fx * (1.0f - fy);
        float w10 = inten * (1.0f - fx) * fy;
        float w11 = inten * fx * fy;
        if ((unsigned)ra < (unsigned)TROWS) {
            atomicAdd(&tile[ra * W + x0], w00);
            atomicAdd(&tile[ra * W + x1], w01);
        }
        if ((unsigned)rb < (unsigned)TROWS) {
            atomicAdd(&tile[rb * W + x0], w10);
            atomicAdd(&tile[rb * W + x1], w11);
        }
    }
    __syncthreads();

    double acc = 0.0;
    for (int i = threadIdx.x; i < TROWS * W / 4; i += 512) {
        float4 sv = t4[i];
        acc += (double)(sv.x * sv.x + sv.y * sv.y) + (double)(sv.z * sv.z + sv.w * sv.w);
    }

    for (int off = 32; off > 0; off >>= 1)
        acc += __shfl_down(acc, off, 64);
    __syncthreads();                             // tile reads done
    double* sacc = (double*)tile;
    int lane = threadIdx.x & 63;
    int wave = threadIdx.x >> 6;
    if (lane == 0) sacc[wave] = acc;
    __syncthreads();
    if (threadIdx.x == 0) {
        double s = 0.0;
        for (int wv = 0; wv < 8; ++wv) s += sacc[wv];
        partials[bid] = s;
    }
}

// ---------------------------------------------------------------------------
// Kernel 3: final reduce of NBUCKETS partials -> mean -> d_out[0]
// ---------------------------------------------------------------------------
__global__ void __launch_bounds__(256) k_final(const double* __restrict__ partials,
                                               float* __restrict__ out) {
    double acc = 0.0;
    for (int i = threadIdx.x; i < NBUCKETS; i += 256)
        acc += partials[i];
    for (int off = 32; off > 0; off >>= 1)
        acc += __shfl_down(acc, off, 64);
    __shared__ double sacc[4];
    int lane = threadIdx.x & 63;
    int wave = threadIdx.x >> 6;
    if (lane == 0) sacc[wave] = acc;
    __syncthreads();
    if (threadIdx.x == 0) {
        double s = sacc[0] + sacc[1] + sacc[2] + sacc[3];
        out[0] = (float)(s / (double)TOT);
    }
}

// ---------------------------------------------------------------------------
extern "C" void kernel_launch(void* const* d_in, const int* in_sizes, int n_in,
                              void* d_out, int out_size, void* d_ws, size_t ws_size,
                              hipStream_t stream) {
    const float* pts = (const float*)d_in[0];     // [B, N, 3]
    const float* tgt = (const float*)d_in[1];     // [B, H, W]
    float* out = (float*)d_out;

    // ws layout: [ counters 16KB | partials 32KB | pad to 64KB | buckets 64MiB ]
    unsigned int* cnt = (unsigned int*)d_ws;
    double* partials = (double*)((char*)d_ws + 16384);
    float4* buckets = (float4*)((char*)d_ws + 65536);

    hipMemsetAsync(cnt, 0, NBUCKETS * sizeof(unsigned int), stream);
    k_bin<<<BIN_BLOCKS, 512, 0, stream>>>((const float4*)pts, buckets, cnt);
    k_tile<<<NBUCKETS, 512, 0, stream>>>(buckets, cnt, tgt, partials);
    k_final<<<1, 256, 0, stream>>>(partials, out);
}

// Round 5
// 86.351 us; speedup vs baseline: 3.0228x; 1.0436x over previous
//
#include <hip/hip_runtime.h>

// Problem constants (match reference)
constexpr int B = 128;
constexpr int N = 16384;
constexpr int H = 512;
constexpr int W = 512;
constexpr int HW = H * W;                        // 262144
constexpr long long TOT = (long long)B * HW;     // 33554432 pixels

constexpr int TROWS = 16;                        // rows per tile (32 KiB LDS)
constexpr int NTILES = H / TROWS;                // 32 tiles per frame
constexpr int NBUCKETS = B * NTILES;             // 4096
constexpr int CAP = 1024;                        // slots per bucket (mean ~545)
constexpr int NGROUPS = B * N / 4;               // 524288 groups of 4 points
constexpr int BIN_BLOCKS = NGROUPS / 512;        // 1024 (2048 pts/block, 8 blk/frame)
constexpr int TILE_F4 = TROWS * W / 4;           // 2048 float4 per tile
constexpr int F4_PER_THREAD = TILE_F4 / 512;     // 4

__device__ __forceinline__ void lds_add(float* p, float v) {
    // force ds_add_f32 (no-return, relaxed, workgroup scope) — avoid CAS lowering
    __hip_atomic_fetch_add(p, v, __ATOMIC_RELAXED, __HIP_MEMORY_SCOPE_WORKGROUP);
}

// ---------------------------------------------------------------------------
// Kernel 1: bin points by (frame, row-tile), per-block LDS slot aggregation.
// Each block handles 2048 points of ONE frame (8 blocks per frame).
// ---------------------------------------------------------------------------
__global__ void __launch_bounds__(512) k_bin(const float4* __restrict__ pts,
                                             float4* __restrict__ buckets,
                                             unsigned int* __restrict__ cnt) {
    __shared__ unsigned int lcnt[NTILES];
    __shared__ unsigned int lbase[NTILES];

    int tid = blockIdx.x * 512 + threadIdx.x;    // one group of 4 points
    int frame = tid >> 12;                       // 4096 groups per frame
    int fb = frame * NTILES;

    if (threadIdx.x < NTILES) lcnt[threadIdx.x] = 0;
    __syncthreads();

    float4 a = pts[tid * 3 + 0];   // x0 y0 i0 x1
    float4 b = pts[tid * 3 + 1];   // y1 i1 x2 y2
    float4 c = pts[tid * 3 + 2];   // i2 x3 y3 i3

    float xs[4] = {a.x, a.w, b.z, c.y};
    float ys[4] = {a.y, b.x, b.w, c.z};
    float is[4] = {a.z, b.y, c.x, c.w};

    int tb0[4], sl0[4], tb1[4], sl1[4];
#pragma unroll
    for (int k = 0; k < 4; ++k) {
        float x = fminf(fmaxf(xs[k], 0.0f), (float)(W - 1));
        float y = fminf(fmaxf(ys[k], 0.0f), (float)(H - 1));
        xs[k] = x; ys[k] = y;
        int y0 = (int)floorf(y);
        int y1 = min(y0 + 1, H - 1);
        int t0 = y0 >> 4;                         // TROWS = 16
        int t1 = y1 >> 4;
        tb0[k] = t0;
        sl0[k] = (int)atomicAdd(&lcnt[t0], 1u);
        if (t1 != t0) {
            tb1[k] = t1;
            sl1[k] = (int)atomicAdd(&lcnt[t1], 1u);
        } else {
            tb1[k] = -1; sl1[k] = 0;
        }
    }
    __syncthreads();

    if (threadIdx.x < NTILES)
        lbase[threadIdx.x] = atomicAdd(&cnt[fb + threadIdx.x], lcnt[threadIdx.x]);
    __syncthreads();

#pragma unroll
    for (int k = 0; k < 4; ++k) {
        float4 rec = make_float4(xs[k], ys[k], is[k], 0.0f);
        unsigned s0 = lbase[tb0[k]] + (unsigned)sl0[k];
        if (s0 < (unsigned)CAP)
            buckets[(size_t)(fb + tb0[k]) * CAP + s0] = rec;
        if (tb1[k] >= 0) {
            unsigned s1 = lbase[tb1[k]] + (unsigned)sl1[k];
            if (s1 < (unsigned)CAP)
                buckets[(size_t)(fb + tb1[k]) * CAP + s1] = rec;
        }
    }
}

// ---------------------------------------------------------------------------
// Kernel 2: per-(frame,tile) block. Zero LDS tile, issue target loads EARLY
// (they fly under the splat phase), splat via ds_add_f32, then (splat-tgt)^2.
// ---------------------------------------------------------------------------
__global__ void __launch_bounds__(512) k_tile(const float4* __restrict__ buckets,
                                              const unsigned int* __restrict__ cnt,
                                              const float* __restrict__ tgt,
                                              double* __restrict__ partials) {
    __shared__ float tile[TROWS * W];            // 32 KiB
    __shared__ double sacc[8];
    int bid = blockIdx.x;
    int frame = bid >> 5;                        // NTILES = 32
    int t = bid & (NTILES - 1);
    int r0 = t * TROWS;

    // phase 1: zero LDS tile (no global traffic)
    float4* t4 = (float4*)tile;
#pragma unroll
    for (int k = 0; k < F4_PER_THREAD; ++k)
        t4[threadIdx.x + k * 512] = make_float4(0.f, 0.f, 0.f, 0.f);

    int n = (int)min(cnt[bid], (unsigned)CAP);
    __syncthreads();

    // issue target loads now — not consumed until after the next barrier,
    // so they complete under the splat phase (issue-early / use-late)
    const float4* tg = (const float4*)(tgt + (size_t)frame * HW + (size_t)r0 * W);
    float4 tv0 = tg[threadIdx.x];
    float4 tv1 = tg[threadIdx.x + 512];
    float4 tv2 = tg[threadIdx.x + 1024];
    float4 tv3 = tg[threadIdx.x + 1536];

    // phase 2: splat this bucket's points into the LDS tile
    const float4* bp = buckets + (size_t)bid * CAP;
    for (int i = threadIdx.x; i < n; i += 512) {
        float4 p = bp[i];
        float x = p.x, y = p.y, inten = p.z;
        float x0f = floorf(x), y0f = floorf(y);
        float fx = x - x0f, fy = y - y0f;
        int x0 = (int)x0f, y0 = (int)y0f;
        int x1 = min(x0 + 1, W - 1);
        int y1 = min(y0 + 1, H - 1);
        int ra = y0 - r0;
        int rb = y1 - r0;
        float w00 = inten * (1.0f - fx) * (1.0f - fy);
        float w01 = inten * fx * (1.0f - fy);
        float w10 = inten * (1.0f - fx) * fy;
        float w11 = inten * fx * fy;
        if ((unsigned)ra < (unsigned)TROWS) {
            lds_add(&tile[ra * W + x0], w00);
            lds_add(&tile[ra * W + x1], w01);
        }
        if ((unsigned)rb < (unsigned)TROWS) {
            lds_add(&tile[rb * W + x0], w10);
            lds_add(&tile[rb * W + x1], w11);
        }
    }
    __syncthreads();    // drains vmcnt (targets in regs) + makes atomics visible

    // phase 3: squared diff, double accumulation (targets already in registers)
    double acc = 0.0;
    {
        float4 sv = t4[threadIdx.x];
        float d0 = sv.x - tv0.x, d1 = sv.y - tv0.y, d2 = sv.z - tv0.z, d3 = sv.w - tv0.w;
        acc += (double)(d0 * d0 + d1 * d1) + (double)(d2 * d2 + d3 * d3);
        sv = t4[threadIdx.x + 512];
        d0 = sv.x - tv1.x; d1 = sv.y - tv1.y; d2 = sv.z - tv1.z; d3 = sv.w - tv1.w;
        acc += (double)(d0 * d0 + d1 * d1) + (double)(d2 * d2 + d3 * d3);
        sv = t4[threadIdx.x + 1024];
        d0 = sv.x - tv2.x; d1 = sv.y - tv2.y; d2 = sv.z - tv2.z; d3 = sv.w - tv2.w;
        acc += (double)(d0 * d0 + d1 * d1) + (double)(d2 * d2 + d3 * d3);
        sv = t4[threadIdx.x + 1536];
        d0 = sv.x - tv3.x; d1 = sv.y - tv3.y; d2 = sv.z - tv3.z; d3 = sv.w - tv3.w;
        acc += (double)(d0 * d0 + d1 * d1) + (double)(d2 * d2 + d3 * d3);
    }

    for (int off = 32; off > 0; off >>= 1)
        acc += __shfl_down(acc, off, 64);
    int lane = threadIdx.x & 63;
    int wave = threadIdx.x >> 6;
    if (lane == 0) sacc[wave] = acc;
    __syncthreads();
    if (threadIdx.x == 0) {
        double s = 0.0;
#pragma unroll
        for (int wv = 0; wv < 8; ++wv) s += sacc[wv];
        partials[bid] = s;
    }
}

// ---------------------------------------------------------------------------
// Kernel 3: final reduce of NBUCKETS partials -> mean -> d_out[0]
// ---------------------------------------------------------------------------
__global__ void __launch_bounds__(256) k_final(const double* __restrict__ partials,
                                               float* __restrict__ out) {
    double acc = 0.0;
    for (int i = threadIdx.x; i < NBUCKETS; i += 256)
        acc += partials[i];
    for (int off = 32; off > 0; off >>= 1)
        acc += __shfl_down(acc, off, 64);
    __shared__ double sacc[4];
    int lane = threadIdx.x & 63;
    int wave = threadIdx.x >> 6;
    if (lane == 0) sacc[wave] = acc;
    __syncthreads();
    if (threadIdx.x == 0) {
        double s = sacc[0] + sacc[1] + sacc[2] + sacc[3];
        out[0] = (float)(s / (double)TOT);
    }
}

// ---------------------------------------------------------------------------
extern "C" void kernel_launch(void* const* d_in, const int* in_sizes, int n_in,
                              void* d_out, int out_size, void* d_ws, size_t ws_size,
                              hipStream_t stream) {
    const float* pts = (const float*)d_in[0];     // [B, N, 3]
    const float* tgt = (const float*)d_in[1];     // [B, H, W]
    float* out = (float*)d_out;

    // ws layout: [ counters 16KB | partials 32KB | pad to 64KB | buckets 64MiB ]
    unsigned int* cnt = (unsigned int*)d_ws;
    double* partials = (double*)((char*)d_ws + 16384);
    float4* buckets = (float4*)((char*)d_ws + 65536);

    hipMemsetAsync(cnt, 0, NBUCKETS * sizeof(unsigned int), stream);
    k_bin<<<BIN_BLOCKS, 512, 0, stream>>>((const float4*)pts, buckets, cnt);
    k_tile<<<NBUCKETS, 512, 0, stream>>>(buckets, cnt, tgt, partials);
    k_final<<<1, 256, 0, stream>>>(partials, out);
}